// Round 1
// baseline (5062.572 us; speedup 1.0000x reference)
//
#include <hip/hip_runtime.h>
#include <hip/hip_bf16.h>
#include <math.h>

#define HIDDEN 256
#define SEQ 2048
#define BATCH 64
#define INSZ 128
#define OUTSZ 64
#define DTC 0.05f

// ---------------- K0: complexity net + alphas ----------------
__global__ __launch_bounds__(1024) void prep_kernel(
    const float* __restrict__ x, const float* __restrict__ cw1, const float* __restrict__ cb1,
    const float* __restrict__ cw2, const float* __restrict__ cb2,
    const float* __restrict__ tau_b, const float* __restrict__ tmw, const float* __restrict__ tmb,
    float* __restrict__ alphas)   // [3][64]
{
    __shared__ float p_lds[8][128];
    __shared__ float xm[128];
    __shared__ float t1[64];
    int b = blockIdx.x;
    int tid = threadIdx.x;
    int c = tid & 127, sh = tid >> 7;
    const float* xb = x + (size_t)b * SEQ * INSZ;
    float s = 0.f;
    for (int t = sh * 256; t < (sh + 1) * 256; ++t) s += xb[(size_t)t * INSZ + c];
    p_lds[sh][c] = s;
    __syncthreads();
    if (tid < 128) {
        float m = 0.f;
        #pragma unroll
        for (int i = 0; i < 8; ++i) m += p_lds[i][tid];
        xm[tid] = m / (float)SEQ;
    }
    __syncthreads();
    if (tid < 64) {
        float acc = cb1[tid];
        for (int k = 0; k < 128; ++k) acc += xm[k] * cw1[tid * 128 + k];
        t1[tid] = fmaxf(acc, 0.f);
    }
    __syncthreads();
    if (tid == 0) {
        float acc = cb2[0];
        for (int k = 0; k < 64; ++k) acc += t1[k] * cw2[k];
        float comp = 1.f / (1.f + expf(-acc));
        for (int i = 0; i < 3; ++i) {
            float lg[4], mx = -1e30f;
            for (int j = 0; j < 4; ++j) { lg[j] = comp * tmw[i * 4 + j] + tmb[i * 4 + j]; mx = fmaxf(mx, lg[j]); }
            float den = 0.f;
            for (int j = 0; j < 4; ++j) { lg[j] = expf(lg[j] - mx); den += lg[j]; }
            float mt = 0.f;
            for (int j = 0; j < 4; ++j) mt += tau_b[i * 4 + j] * (lg[j] / den);
            alphas[i * 64 + b] = expf(-DTC / mt);
        }
    }
}

// ---------------- streaming register-weight GEMM ----------------
// C[m][0:256] = A[m][0:K] @ W[256][K]^T + bias, rows streamed per WG.
// KQ = K/64 k-blocks; NR outputs per thread. 512 threads.
// In-place safe (C may alias A): each WG stages its rows in LDS before writing.
template<int KQ, int NR>
__global__ __launch_bounds__(512) void gemm_stream(
    const float* A, const float* __restrict__ W, const float* __restrict__ bias,
    float* C, int rows_per_wg)
{
    constexpr int K = KQ * 64;
    constexpr int JB = 8 / KQ;
    __shared__ float a_lds[4 * K];
    __shared__ float p_lds[KQ][4][256];
    __shared__ float bias_l[256];
    int tid = threadIdx.x;
    int w = tid >> 6, l = tid & 63;
    int q = w % KQ, jb = w / KQ;

    float4 wr[NR][16];
    #pragma unroll
    for (int r = 0; r < NR; ++r) {
        int j = jb * 64 + l + r * (JB * 64);
        const float4* wp = (const float4*)(W + (size_t)j * K + q * 64);
        #pragma unroll
        for (int m = 0; m < 16; ++m) wr[r][m] = wp[m];
    }
    if (tid < 256) bias_l[tid] = bias[tid];

    size_t row0 = (size_t)blockIdx.x * rows_per_wg;
    for (int it = 0; it < rows_per_wg; it += 4) {
        size_t m0 = row0 + it;
        __syncthreads();  // protect a_lds/p_lds from previous iteration readers
        #pragma unroll
        for (int e = 0; e < K / 128; ++e)
            a_lds[tid + e * 512] = A[m0 * K + tid + e * 512];
        __syncthreads();

        float acc[4][NR];
        #pragma unroll
        for (int r4 = 0; r4 < 4; ++r4)
            #pragma unroll
            for (int r = 0; r < NR; ++r) acc[r4][r] = 0.f;

        #pragma unroll
        for (int r4 = 0; r4 < 4; ++r4) {
            const float4* hp = (const float4*)(a_lds + r4 * K + q * 64);
            #pragma unroll
            for (int m = 0; m < 16; ++m) {
                float4 hv = hp[m];
                #pragma unroll
                for (int r = 0; r < NR; ++r) {
                    acc[r4][r] = fmaf(wr[r][m].x, hv.x, acc[r4][r]);
                    acc[r4][r] = fmaf(wr[r][m].y, hv.y, acc[r4][r]);
                    acc[r4][r] = fmaf(wr[r][m].z, hv.z, acc[r4][r]);
                    acc[r4][r] = fmaf(wr[r][m].w, hv.w, acc[r4][r]);
                }
            }
        }
        #pragma unroll
        for (int r4 = 0; r4 < 4; ++r4)
            #pragma unroll
            for (int r = 0; r < NR; ++r)
                p_lds[q][r4][jb * 64 + l + r * (JB * 64)] = acc[r4][r];
        __syncthreads();
        if (tid < 256) {
            #pragma unroll
            for (int r4 = 0; r4 < 4; ++r4) {
                float s2 = bias_l[tid];
                #pragma unroll
                for (int qq = 0; qq < KQ; ++qq) s2 += p_lds[qq][r4][tid];
                C[(m0 + r4) * 256 + tid] = s2;
            }
        }
    }
}

// ---------------- sequential scan, one WG per batch element ----------------
// In-place: reads ext[t] (prefetched one step ahead), writes h[t] over it.
__global__ __launch_bounds__(512) void scan_kernel(
    float* buf,                       // [B][S][256]: in = ext, out = h_seq (in place)
    const float* __restrict__ W_rec,  // [256][256]
    const float* __restrict__ alphas, // [64]
    float* __restrict__ h_carry,      // [64][256]
    int layer, int write_all)
{
    __shared__ float h_lds[2][256];
    __shared__ float p_lds[4][256];
    int b = blockIdx.x;
    int tid = threadIdx.x;
    int w = tid >> 6, l = tid & 63;
    int q = w & 3, jb = w >> 2;

    float4 wr[2][16];
    #pragma unroll
    for (int r = 0; r < 2; ++r) {
        int j = jb * 64 + l + r * 128;
        const float4* wp = (const float4*)(W_rec + (size_t)j * 256 + q * 64);
        #pragma unroll
        for (int m = 0; m < 16; ++m) wr[r][m] = wp[m];
    }
    float alpha = alphas[b];
    float onema = 1.f - alpha;
    float* bb = buf + (size_t)b * SEQ * HIDDEN;

    float h_reg = 0.f, e_cur = 0.f;
    if (tid < 256) {
        h_reg = (layer == 0) ? 0.f : h_carry[b * 256 + tid];
        h_lds[0][tid] = h_reg;
        e_cur = bb[tid];   // ext[0]
    }
    __syncthreads();

    int cur = 0;
    for (int t = 0; t < SEQ; ++t) {
        float e_next = 0.f;
        if (tid < 256 && t + 1 < SEQ) e_next = bb[(size_t)(t + 1) * HIDDEN + tid];

        float acc0 = 0.f, acc1 = 0.f;
        const float4* hp = (const float4*)(&h_lds[cur][q * 64]);
        #pragma unroll
        for (int m = 0; m < 16; ++m) {
            float4 hv = hp[m];
            acc0 = fmaf(wr[0][m].x, hv.x, acc0);
            acc0 = fmaf(wr[0][m].y, hv.y, acc0);
            acc0 = fmaf(wr[0][m].z, hv.z, acc0);
            acc0 = fmaf(wr[0][m].w, hv.w, acc0);
            acc1 = fmaf(wr[1][m].x, hv.x, acc1);
            acc1 = fmaf(wr[1][m].y, hv.y, acc1);
            acc1 = fmaf(wr[1][m].z, hv.z, acc1);
            acc1 = fmaf(wr[1][m].w, hv.w, acc1);
        }
        p_lds[q][jb * 64 + l] = acc0;
        p_lds[q][jb * 64 + l + 128] = acc1;
        __syncthreads();
        if (tid < 256) {
            float s2 = p_lds[0][tid] + p_lds[1][tid] + p_lds[2][tid] + p_lds[3][tid] + e_cur;
            float act = tanhf(s2);
            h_reg = alpha * h_reg + onema * act;
            h_lds[cur ^ 1][tid] = h_reg;
            if (write_all) bb[(size_t)t * HIDDEN + tid] = h_reg;
            if (t == SEQ - 1) h_carry[b * 256 + tid] = h_reg;
        }
        __syncthreads();
        cur ^= 1;
        e_cur = e_next;
    }
}

// ---------------- final projection from h_carry ----------------
__global__ __launch_bounds__(256) void outproj_kernel(
    const float* __restrict__ h_carry, const float* __restrict__ ow, const float* __restrict__ ob,
    float* __restrict__ out)
{
    __shared__ float h_l[256];
    __shared__ float p_lds[4][64];
    int b = blockIdx.x;
    int tid = threadIdx.x;
    h_l[tid] = h_carry[b * 256 + tid];
    __syncthreads();
    int o = tid & 63, qq = tid >> 6;
    float s = 0.f;
    const float4* wp = (const float4*)(ow + o * 256 + qq * 64);
    const float4* hp = (const float4*)(h_l + qq * 64);
    #pragma unroll
    for (int m = 0; m < 16; ++m) {
        float4 wv = wp[m]; float4 hv = hp[m];
        s = fmaf(wv.x, hv.x, s); s = fmaf(wv.y, hv.y, s);
        s = fmaf(wv.z, hv.z, s); s = fmaf(wv.w, hv.w, s);
    }
    p_lds[qq][o] = s;
    __syncthreads();
    if (tid < 64)
        out[b * 64 + tid] = p_lds[0][tid] + p_lds[1][tid] + p_lds[2][tid] + p_lds[3][tid] + ob[tid];
}

extern "C" void kernel_launch(void* const* d_in, const int* in_sizes, int n_in,
                              void* d_out, int out_size, void* d_ws, size_t ws_size,
                              hipStream_t stream)
{
    const float* x     = (const float*)d_in[0];
    const float* cw1   = (const float*)d_in[1];
    const float* cb1   = (const float*)d_in[2];
    const float* cw2   = (const float*)d_in[3];
    const float* cb2   = (const float*)d_in[4];
    const float* pw    = (const float*)d_in[5];
    const float* pb    = (const float*)d_in[6];
    const float* W_rec = (const float*)d_in[7];
    const float* W_in  = (const float*)d_in[8];
    const float* bias  = (const float*)d_in[9];
    const float* tau_b = (const float*)d_in[10];
    const float* tmw   = (const float*)d_in[11];
    const float* tmb   = (const float*)d_in[12];
    const float* ow    = (const float*)d_in[13];
    const float* ob    = (const float*)d_in[14];
    float* out = (float*)d_out;

    char* ws = (char*)d_ws;
    float* alphas  = (float*)ws;                    // 192 floats
    float* h_carry = (float*)(ws + 4096);           // 64*256 floats
    float* buf     = (float*)(ws + 131072);         // [64][2048][256] fp32 = 134 MB

    const int M = BATCH * SEQ;          // 131072 rows
    const int ROWS_PER_WG = M / 256;    // 512

    prep_kernel<<<64, 1024, 0, stream>>>(x, cw1, cb1, cw2, cb2, tau_b, tmw, tmb, alphas);
    // input projection: buf = x @ pw.T + pb
    gemm_stream<2, 1><<<256, 512, 0, stream>>>(x, pw, pb, buf, ROWS_PER_WG);
    for (int i = 0; i < 3; ++i) {
        // ext = h_seq @ W_in[i].T + bias[i]   (in place on buf)
        gemm_stream<4, 2><<<256, 512, 0, stream>>>(buf, W_in + (size_t)i * HIDDEN * HIDDEN,
                                                   bias + i * HIDDEN, buf, ROWS_PER_WG);
        // recurrence (in place: h[t] overwrites ext[t])
        scan_kernel<<<64, 512, 0, stream>>>(buf, W_rec + (size_t)i * HIDDEN * HIDDEN,
                                            alphas + i * 64, h_carry, i, (i < 2) ? 1 : 0);
    }
    outproj_kernel<<<64, 256, 0, stream>>>(h_carry, ow, ob, out);
}